// Round 5
// baseline (34.467 us; speedup 1.0000x reference)
//
#include <hip/hip_runtime.h>

// ---------------------------------------------------------------------------
// TimeLSTMCell fused kernel for MI355X (gfx950) — round 7
// B=4096, D=256, U=512; out = concat(h, c_m) fp32
//
// ROUND 7: deep-lookahead redesign (the controlled version of r5).
//   Evidence: locality / LDS-read / sync-slack levers all ~neutral; per-step
//   throughput models say ~7us but loop measures ~23us -> per-step MEMORY
//   LATENCY exposure (1-step lookahead, lockstep barriers) is the binding
//   cost. Fix latency tolerance with pipeline DEPTH:
//   - main: 128x64 tile (A staging traffic halves, 189->141 MB), BK=32,
//     3-buffer LDS ring, stage(s+2) issued 2 steps ahead, counted vmcnt
//     leaves 6-8 loads in flight (never 0 until drain). 512 thr / 8 waves
//     (2/SIMD, same wave count as r6), 84KB LDS, grid 256 (1 block/CU).
//   - prep: BK=32 tiles (A 128x32, B1 320x32, B2 192x32), swizzle
//     kc ^ ((r>>1)&3): B-reads 2-way bank aliasing (free), A whole-row
//     balanced. Same workspace offsets/sizes as before.
// ---------------------------------------------------------------------------

typedef __attribute__((ext_vector_type(8))) short short8_t;   // 8 bf16
typedef __attribute__((ext_vector_type(4))) float f32x4_t;
typedef unsigned int u32;

#define B_N 4096
#define D_K 256
#define U_N 512

__device__ __forceinline__ unsigned short f2bf(float f) {
    unsigned int x = __float_as_uint(f);
    unsigned int r = x + 0x7fffu + ((x >> 16) & 1u);   // RNE
    return (unsigned short)(r >> 16);
}

__device__ __forceinline__ float sigf(float z) {
    return 1.0f / (1.0f + __expf(-z));
}

// fast tanh: exact at +/-inf, ~1e-7 abs err
__device__ __forceinline__ float tanhfast(float z) {
    return 1.0f - 2.0f / (1.0f + __expf(2.0f * z));
}

__device__ __forceinline__ void gl16(const unsigned short* g, unsigned short* l) {
    __builtin_amdgcn_global_load_lds(
        (const __attribute__((address_space(1))) u32*)g,
        (__attribute__((address_space(3))) u32*)l, 16, 0, 0);
}

// BK=32 swizzled element offset of (row r, k-chunk kc), 4 chunks (16B) per row
#define SWZ32(r, kc) ((((r) * 4) + ((kc) ^ (((r) >> 1) & 3))) * 8)

// counted vmcnt wait + scheduling fence (compile-time literal N)
#define WAIT_VM(N)                                            \
    asm volatile("s_waitcnt vmcnt(" #N ")" ::: "memory");     \
    __builtin_amdgcn_sched_barrier(0)

// ---------------------------------------------------------------------------
// prepass: BK=32 tiles, 4 segments by flat 16B-chunk id
//   xs : A tiles 128x32 (512 ch),  t = rb*8  + kb, rb 0..31, kb 0..7
//   hs : A tiles 128x32 (512 ch),  t = rb*16 + kb, rb 0..31, kb 0..15
//   ksw: B1 tiles 320x32 (1280 ch), t = nb*8  + kb, nb 0..7,  kb 0..7
//        row r = m*64 + cc (m gate 0..4, cc col-in-block 0..63)
//   rsw: B2 tiles 192x32 (768 ch),  t = nb*16 + kb, nb 0..7,  kb 0..15
// chunks: 131072 + 262144 + 81920 + 98304 = 573440 = 2240 blocks x 256
// ---------------------------------------------------------------------------
__global__ __launch_bounds__(256) void prep(
    const float* __restrict__ x, const float* __restrict__ h0,
    const float* __restrict__ kern, const float* __restrict__ rk,
    unsigned short* __restrict__ xs, unsigned short* __restrict__ hs,
    unsigned short* __restrict__ ksw, unsigned short* __restrict__ rsw)
{
    const int c = blockIdx.x * 256 + threadIdx.x;
    if (c < 131072) {                       // ---- x ----
        const int t = c >> 9, q = c & 511;
        const int row = q >> 2, kc = q & 3;
        const int rb = t >> 3, kb = t & 7;
        const float* s = x + (size_t)(rb * 128 + row) * D_K + kb * 32 + kc * 8;
        short8_t o;
#pragma unroll
        for (int j = 0; j < 8; ++j) o[j] = (short)f2bf(s[j]);
        *reinterpret_cast<short8_t*>(xs + (size_t)t * 4096 + SWZ32(row, kc)) = o;
    } else if (c < 393216) {                // ---- h0 ----
        const int c2 = c - 131072;
        const int t = c2 >> 9, q = c2 & 511;
        const int row = q >> 2, kc = q & 3;
        const int rb = t >> 4, kb = t & 15;
        const float* s = h0 + (size_t)(rb * 128 + row) * U_N + kb * 32 + kc * 8;
        short8_t o;
#pragma unroll
        for (int j = 0; j < 8; ++j) o[j] = (short)f2bf(s[j]);
        *reinterpret_cast<short8_t*>(hs + (size_t)t * 4096 + SWZ32(row, kc)) = o;
    } else if (c < 475136) {                // ---- kernel (transpose) ----
        const int c2 = c - 393216;
        const int t = c2 / 1280, q = c2 - t * 1280;
        const int kc = q / 320, r = q - kc * 320;     // r = m*64 + cc
        const int nb = t >> 3, kb = t & 7;
        const int col = (r >> 6) * U_N + nb * 64 + (r & 63);
        short8_t o;
#pragma unroll
        for (int j = 0; j < 8; ++j)
            o[j] = (short)f2bf(kern[(size_t)(kb * 32 + kc * 8 + j) * 2560 + col]);
        *reinterpret_cast<short8_t*>(ksw + (size_t)t * 10240 + SWZ32(r, kc)) = o;
    } else {                                // ---- rk (transpose) ----
        const int c2 = c - 475136;
        const int t = c2 / 768, q = c2 - t * 768;
        const int kc = q / 192, r = q - kc * 192;     // r = m*64 + cc
        const int nb = t >> 4, kb = t & 15;
        const int col = (r >> 6) * U_N + nb * 64 + (r & 63);
        short8_t o;
#pragma unroll
        for (int j = 0; j < 8; ++j)
            o[j] = (short)f2bf(rk[(size_t)(kb * 32 + kc * 8 + j) * 1536 + col]);
        *reinterpret_cast<short8_t*>(rsw + (size_t)t * 6144 + SWZ32(r, kc)) = o;
    }
}

// ---------------------------------------------------------------------------
// main fused kernel
// grid (8, 32) = 256 blocks (1/CU), 512 threads (8 waves, 2/SIMD)
// wave (wm, wn) = (wave>>2, wave&3): rows [64*wm,+64) x cols [16*wn,+16)
// of the 128x64 band, for every stacked gate matrix.
// 24 K-steps of BK=32 (8 phase1 + 16 phase2); 3-buffer ring, 2-step lookahead.
// ---------------------------------------------------------------------------
__global__ __launch_bounds__(512, 2) void tlstm_main(
    const unsigned short* __restrict__ xs,    // swizzled x tiles
    const unsigned short* __restrict__ hs,    // swizzled h0 tiles
    const unsigned short* __restrict__ ksw,   // swizzled kernel^T tiles
    const unsigned short* __restrict__ rsw,   // swizzled rk^T tiles
    const float* __restrict__ tvec,           // [4096]
    const float* __restrict__ c0,             // [4096][512]
    const float* __restrict__ ktime,          // [1536] cols [t1,t2,o]
    float* __restrict__ out)                  // h, then c_m
{
    // per buffer: A 4096 elems (8KB) + B 10240 elems (20KB) = 28KB; x3 = 84KB
    __shared__ __align__(16) unsigned short lds[3][14336];

    const int tid = threadIdx.x;
    const int wave = tid >> 6;
    const int lane = tid & 63;
    const int lr = lane & 15;
    const int lq = lane >> 4;
    const int wm = wave >> 2;                 // 0..1 : 64-row half
    const int wn = wave & 3;                  // 0..3 : 16-col slice
    const int nb = blockIdx.x;                // 0..7  (64-col blocks)
    const int rb = blockIdx.y;                // 0..31 (128-row blocks)

    const int u = nb * 64 + wn * 16 + lr;     // output column

    // acc[m][p]: gate m (0..4 = x@K, 5..7 = h0@RK), row frag p (wm*64+p*16)
    f32x4_t acc[8][4];
#pragma unroll
    for (int m = 0; m < 8; ++m)
#pragma unroll
        for (int p = 0; p < 4; ++p)
            acc[m][p] = (f32x4_t){0.f, 0.f, 0.f, 0.f};

    // ---- staging: linear global_load_lds, wave-uniform LDS dest ----
    // per-wave vmem issues: phase1 (s<8): 1 A + 3 B = 4; phase2: 1 A + 2 B = 3
    // (B chunk counts 1280/768 aren't 512-multiples; the last B issue makes
    //  waves >=4 re-stage their first-chunk range — same src -> same dest,
    //  harmless, keeps per-wave vmcnt counts uniform.)
    auto stage = [&](int s, int buf) {
        unsigned short* ab = &lds[buf][0];
        unsigned short* bb = &lds[buf][4096];
        if (s < 8) {
            const unsigned short* at = xs + (size_t)(rb * 8 + s) * 4096;
            gl16(at + (size_t)tid * 8, ab + (size_t)(wave * 64) * 8);
            const unsigned short* bt = ksw + (size_t)(nb * 8 + s) * 10240;
            gl16(bt + (size_t)tid * 8,         bb + (size_t)(wave * 64) * 8);
            gl16(bt + (size_t)(512 + tid) * 8, bb + (size_t)(512 + wave * 64) * 8);
            const int b3 = (wave < 4) ? (1024 + wave * 64) : (wave * 64);
            gl16(bt + (size_t)(b3 + lane) * 8, bb + (size_t)b3 * 8);
        } else {
            const unsigned short* at = hs + (size_t)(rb * 16 + (s - 8)) * 4096;
            gl16(at + (size_t)tid * 8, ab + (size_t)(wave * 64) * 8);
            const unsigned short* bt = rsw + (size_t)(nb * 16 + (s - 8)) * 6144;
            gl16(bt + (size_t)tid * 8, bb + (size_t)(wave * 64) * 8);
            const int b2 = (wave < 4) ? (512 + wave * 64) : (wave * 64);
            gl16(bt + (size_t)(b2 + lane) * 8, bb + (size_t)b2 * 8);
        }
    };

    auto compute1 = [&](int buf) {      // x @ kernel -> acc[0..4]
        const unsigned short* ab = &lds[buf][0];
        const unsigned short* bb = &lds[buf][4096];
        short8_t a[4];
#pragma unroll
        for (int p = 0; p < 4; ++p)
            a[p] = *reinterpret_cast<const short8_t*>(ab + SWZ32(wm * 64 + p * 16 + lr, lq));
#pragma unroll
        for (int m = 0; m < 5; ++m) {
            const int r = m * 64 + wn * 16 + lr;
            short8_t b = *reinterpret_cast<const short8_t*>(bb + SWZ32(r, lq));
#pragma unroll
            for (int p = 0; p < 4; ++p)
                acc[m][p] = __builtin_amdgcn_mfma_f32_16x16x32_bf16(a[p], b, acc[m][p], 0, 0, 0);
        }
    };

    auto compute2 = [&](int buf) {      // h0 @ rk -> acc[5..7]
        const unsigned short* ab = &lds[buf][0];
        const unsigned short* bb = &lds[buf][4096];
        short8_t a[4];
#pragma unroll
        for (int p = 0; p < 4; ++p)
            a[p] = *reinterpret_cast<const short8_t*>(ab + SWZ32(wm * 64 + p * 16 + lr, lq));
#pragma unroll
        for (int m = 0; m < 3; ++m) {
            const int r = m * 64 + wn * 16 + lr;
            short8_t b = *reinterpret_cast<const short8_t*>(bb + SWZ32(r, lq));
#pragma unroll
            for (int p = 0; p < 4; ++p)
                acc[5 + m][p] = __builtin_amdgcn_mfma_f32_16x16x32_bf16(a[p], b, acc[5 + m][p], 0, 0, 0);
        }
    };

    // step S: issue stage(S+2) (2-step lookahead), wait until tile S landed
    // (NV = in-flight loads of tiles S+1,S+2), barrier, compute, barrier
    // (trailing barrier releases buffer (S)%3 for stage(S+3) next step... and
    //  protects buffer (S+2)%3 == (S-1)%3 overwrite: it was released by the
    //  barrier at the end of step S-1).
#define K_STEP(S, NV, CF)                                  \
    {                                                      \
        stage((S) + 2, ((S) + 2) % 3);                     \
        WAIT_VM(NV);                                       \
        __builtin_amdgcn_s_barrier();                      \
        __builtin_amdgcn_sched_barrier(0);                 \
        CF((S) % 3);                                       \
        __builtin_amdgcn_sched_barrier(0);                 \
        __builtin_amdgcn_s_barrier();                      \
        __builtin_amdgcn_sched_barrier(0);                 \
    }
#define K_TAIL(S, NV, CF)                                  \
    {                                                      \
        WAIT_VM(NV);                                       \
        __builtin_amdgcn_s_barrier();                      \
        __builtin_amdgcn_sched_barrier(0);                 \
        CF((S) % 3);                                       \
        __builtin_amdgcn_sched_barrier(0);                 \
        __builtin_amdgcn_s_barrier();                      \
        __builtin_amdgcn_sched_barrier(0);                 \
    }

    // ---- ring-pipelined K-loop: 24 steps, per-wave L = [4 x8, 3 x16] ----
    stage(0, 0);
    stage(1, 1);
    K_STEP(0, 8, compute1);    // in flight: t1(4)+t2(4)
    K_STEP(1, 8, compute1);
    K_STEP(2, 8, compute1);
    K_STEP(3, 8, compute1);
    K_STEP(4, 8, compute1);
    K_STEP(5, 8, compute1);
    K_STEP(6, 7, compute1);    // t7(4)+t8(3)
    K_STEP(7, 6, compute1);    // t8(3)+t9(3)
    K_STEP(8, 6, compute2);
    K_STEP(9, 6, compute2);
    K_STEP(10, 6, compute2);
    K_STEP(11, 6, compute2);
    K_STEP(12, 6, compute2);
    K_STEP(13, 6, compute2);
    K_STEP(14, 6, compute2);
    K_STEP(15, 6, compute2);
    K_STEP(16, 6, compute2);
    K_STEP(17, 6, compute2);
    K_STEP(18, 6, compute2);
    K_STEP(19, 6, compute2);
    K_STEP(20, 6, compute2);
    K_STEP(21, 6, compute2);   // stages tile 23 (last)
    K_TAIL(22, 3, compute2);   // only t23(3) in flight
    K_TAIL(23, 0, compute2);

    // ---- epilogue: TimeLSTM elementwise (fp32) ----
    const float NEG_EPS = -1e-5f;
    const float kt1 = ktime[u];
    const float kt2 = ktime[U_N + u];
    const float kto = ktime[2 * U_N + u];
#pragma unroll
    for (int p = 0; p < 4; ++p)
#pragma unroll
        for (int i2 = 0; i2 < 4; ++i2) {
            const int b = rb * 128 + wm * 64 + p * 16 + lq * 4 + i2;
            const float tb = tvec[b];
            const float c0v = c0[(size_t)b * U_N + u];
            const float x_i  = acc[0][p][i2];
            const float x_c  = acc[1][p][i2];
            const float x_o  = acc[2][p][i2];
            const float x_t1 = acc[3][p][i2];
            const float x_t2 = acc[4][p][i2];
            const float r_i  = acc[5][p][i2];
            const float r_c  = acc[6][p][i2];
            const float r_o  = acc[7][p][i2];

            const float ig  = sigf(x_i + r_i);
            const float t1v = sigf(x_t1 + sigf(tb * kt1));
            const float t1c = (t1v > NEG_EPS) ? NEG_EPS : t1v;
            const float t2v = sigf(x_t2 + sigf(tb * kt2));
            const float ct  = tanhfast(x_c + r_c);
            const float cm_ = (1.f - ig * t1v) * c0v + ig * ct * t1c;
            const float cm  = (1.f - ig) * c0v + ig * ct * t2v;
            const float og  = sigf(x_o + r_o + tb * kto);

            out[(size_t)b * U_N + u] = tanhfast(cm_) * og;
            out[(size_t)B_N * U_N + (size_t)b * U_N + u] = cm;
        }
}

// ---------------------------------------------------------------------------
extern "C" void kernel_launch(void* const* d_in, const int* in_sizes, int n_in,
                              void* d_out, int out_size, void* d_ws, size_t ws_size,
                              hipStream_t stream) {
    const float* x     = (const float*)d_in[0];   // [4096][256]
    const float* t     = (const float*)d_in[1];   // [4096][1]
    const float* h0    = (const float*)d_in[2];   // [4096][512]
    const float* c0    = (const float*)d_in[3];   // [4096][512]
    const float* kern  = (const float*)d_in[4];   // [256][2560]
    const float* rk    = (const float*)d_in[5];   // [512][1536]
    const float* ktime = (const float*)d_in[6];   // [1][1536]
    float* out = (float*)d_out;

    // ws layout (bytes):
    //   xs  @ 0        : 4096*256*2  = 2,097,152  (swizzled 128x32 tiles)
    //   hs  @ 2097152  : 4096*512*2  = 4,194,304
    //   ksw @ 6291456  : 2560*256*2  = 1,310,720  (swizzled 320x32 tiles)
    //   rsw @ 7602176  : 1536*512*2  = 1,572,864  (swizzled 192x32 tiles)
    unsigned short* xs  = (unsigned short*)d_ws;
    unsigned short* hs  = (unsigned short*)((char*)d_ws + 2097152);
    unsigned short* ksw = (unsigned short*)((char*)d_ws + 6291456);
    unsigned short* rsw = (unsigned short*)((char*)d_ws + 7602176);

    prep<<<2240, 256, 0, stream>>>(x, h0, kern, rk, xs, hs, ksw, rsw);
    tlstm_main<<<dim3(8, 32), 512, 0, stream>>>(
        xs, hs, ksw, rsw, t, c0, ktime, out);
}